// Round 1
// baseline (495.259 us; speedup 1.0000x reference)
//
#include <hip/hip_runtime.h>

// CustomAttention: out = softmax((x_t Wq^T + bq)(x_nt Wk^T + bk)^T) (x_nt Wv^T + bv)
// B=8, SQ=SKV=2048, D=1024. fp32 in/out, fp16 MFMA compute (fp32 accumulate).
//
// Round 3: replace the 128x128 / 2-barrier-per-K-step GEMM (841 TF, MfmaUtil 37%,
// barrier-drain-bound) with a 256x256 deep-pipelined schedule:
//  - 8 waves (2M x 4N), per-wave 128x64 output, acc[8][4] f32x4.
//  - K processed in 32-wide slices (kappa). LDS = 4-slot ring per operand
//    (slot = 16 KB = 256 rows x 32 halfs), 128 KiB total.
//  - Each kappa = 2 phases (m-frag quadrants). Per phase: 8-or-4 ds_read_b128
//    fragment loads + 2 global_load_lds staging slice kappa+3, raw s_barrier,
//    lgkmcnt(0), setprio(1), 16x mfma_f32_16x16x32_f16, setprio(0).
//  - s_waitcnt vmcnt(8) ONLY at slice boundaries: 8 loads (2 slice-pairs)
//    remain in flight across every barrier; never drains to 0 in the loop.
//    Ring safety: slot (k+3)&3 == (k-1)&3 whose last ds_read completed before
//    the previous phase's end barrier. Tail: staging clamps to NK-1 and
//    re-writes identical bytes (benign) to keep vmcnt accounting uniform.
//  - Zero-conflict granule-XOR LDS layout preserved: physical 128 rows x 64
//    halfs per slot (row l packs M-rows {2l,2l+1}), granule g_phys = g ^ (l&7);
//    global source pre-swizzled so global_load_lds dest stays linear.
//
// ws layout (224 MiB peak + 6 MiB weights):
//  [0,32)    tgt16   -- dead after projections | S16 [0,64) written by QK
//  [32,64)   ntg16   -- dead after projections |
//  [64,128)  P16     (written by softmax)
//  [128,160) Q16
//  [160,192) K16
//  [192,224) Vt16
//  [224,230) Wq16/Wk16/Wv16

typedef _Float16 half8 __attribute__((ext_vector_type(8)));
typedef _Float16 half4v __attribute__((ext_vector_type(4)));
typedef float floatx4 __attribute__((ext_vector_type(4)));

__device__ __forceinline__ void async_copy16(const _Float16* g, _Float16* l) {
  __builtin_amdgcn_global_load_lds(
      (const __attribute__((address_space(1))) void*)g,
      (__attribute__((address_space(3))) void*)l,
      16, 0, 0);
}

// ---------------- cast fp32 -> fp16 (8 elems/thread) ----------------
__global__ __launch_bounds__(256) void cast_f32_f16(const float* __restrict__ src,
                                                    _Float16* __restrict__ dst, long n) {
  long i = ((long)blockIdx.x * 256 + threadIdx.x) * 8;
  if (i >= n) return;
  float4 a = *(const float4*)(src + i);
  float4 b = *(const float4*)(src + i + 4);
  half8 h;
  h[0] = (_Float16)a.x; h[1] = (_Float16)a.y; h[2] = (_Float16)a.z; h[3] = (_Float16)a.w;
  h[4] = (_Float16)b.x; h[5] = (_Float16)b.y; h[6] = (_Float16)b.z; h[7] = (_Float16)b.w;
  *(half8*)(dst + i) = h;
}

// ---------------- fp16 BT GEMM, 256x256 tile, pipelined ring ----------------
// C[m,n] = sum_k A[m,k]*B[n,k] (+bias[n])
// OMODE 0: fp16 out row-major [*,N] + bias
// OMODE 1: fp16 out V-transposed: row r -> (b=r>>11, s=r&2047), Vt[b][n][s], + bias
// OMODE 2: fp32 out row-major [*,N] per batch (no bias)
// OMODE 3: fp16 out row-major [*,N] per batch (no bias)  [S scores]
template <int OMODE>
__global__ __launch_bounds__(512, 2) void gemm256(const _Float16* __restrict__ A,
                                                  const _Float16* __restrict__ Bm,
                                                  const float* __restrict__ bias,
                                                  void* __restrict__ out,
                                                  int K, int N,
                                                  long sA, long sB, long sO) {
  // A-ring: 4 slots x 8192 halfs; B-ring same. 128 KiB.
  __shared__ __attribute__((aligned(16))) _Float16 lds[65536];
  _Float16* Ar = lds;
  _Float16* Br = lds + 32768;

  const int tid = threadIdx.x;
  const int lane = tid & 63;
  const int wave = tid >> 6;
  const int wm = wave >> 2;   // 0..1  (M half)
  const int wn = wave & 3;    // 0..3  (N quarter)
  const int frow = lane & 15;
  const int fq = (lane >> 4) & 3;
  const long bz = blockIdx.z;

  const _Float16* Ab = A + bz * sA + (long)blockIdx.x * 256 * K;
  const _Float16* Bb = Bm + bz * sB + (long)blockIdx.y * 256 * K;

  // Staging: slice = 256 rows x 32 halfs = 1024 x 16B chunks; thread owns
  // chunks c = tid + 512j (j=0,1). Physical chunk c -> lds row l=c>>3,
  // phys granule c&7; logical granule = (c&7) ^ (l&7); global (row,k):
  // row = 2l + (glog>>2), k-granule = glog&3. 512j keeps l&7 and c&7 fixed.
  const int glog = (tid & 7) ^ ((tid >> 3) & 7);
  const long sg = (long)(2 * (tid >> 3) + (glog >> 2)) * K + (glog & 3) * 8;
  const int ldst = tid * 8;            // halfs within slot; j adds 4096
  const long lK128 = (long)K * 128;    // j=1 adds 128 M-rows

  // Fragment reads: logical (R, fq) -> l = R>>1, g = (R&1)*4+fq,
  // g_phys = g ^ (l&7). All frag bases are multiples of 16 rows -> l&7 = frow>>1.
  const int gphys = ((frow & 1) * 4 + fq) ^ (frow >> 1);
  const int aoff = (frow >> 1) * 64 + gphys * 8;  // lane-invariant across frags

  floatx4 acc[8][4];
#pragma unroll
  for (int m = 0; m < 8; ++m)
#pragma unroll
    for (int n = 0; n < 4; ++n) acc[m][n] = (floatx4){0.f, 0.f, 0.f, 0.f};

  const int NK = K >> 5;  // 32-wide K slices (32 or 64 here)

  // Prologue: stage slices 0,1,2 (A+B each: 2 loads) = 12 loads.
  // vmcnt(8) -> oldest 4 (all of slice 0, A and B) landed.
#pragma unroll
  for (int kp = 0; kp < 3; ++kp) {
#pragma unroll
    for (int j = 0; j < 2; ++j)
      async_copy16(Ab + sg + kp * 32 + j * lK128, Ar + kp * 8192 + ldst + j * 4096);
#pragma unroll
    for (int j = 0; j < 2; ++j)
      async_copy16(Bb + sg + kp * 32 + j * lK128, Br + kp * 8192 + ldst + j * 4096);
  }
  asm volatile("s_waitcnt vmcnt(8)" ::: "memory");
  __builtin_amdgcn_s_barrier();

  for (int kc = 0; kc < NK; ++kc) {
    const int slot = kc & 3;
    int ks = kc + 3;
    if (ks > NK - 1) ks = NK - 1;  // tail: duplicate staging, identical bytes
    const int ssl = ks & 3;
    const _Float16* as = Ar + slot * 8192 + wm * 4096 + aoff;
    const _Float16* bs = Br + slot * 8192 + wn * 2048 + aoff;

    half8 af[4], bf[4];

    // -------- phase even (qm=0): m-frags 0..3, load bf (reused by odd) ------
#pragma unroll
    for (int i = 0; i < 4; ++i) af[i] = *(const half8*)(as + i * 512);
#pragma unroll
    for (int n = 0; n < 4; ++n) bf[n] = *(const half8*)(bs + n * 512);
#pragma unroll
    for (int j = 0; j < 2; ++j)  // stage A(ks): slot (kc-1)&3, reads done last phase
      async_copy16(Ab + sg + ks * 32 + j * lK128, Ar + ssl * 8192 + ldst + j * 4096);
    __builtin_amdgcn_s_barrier();
    asm volatile("s_waitcnt lgkmcnt(0)" ::: "memory");
    __builtin_amdgcn_sched_barrier(0);
    __builtin_amdgcn_s_setprio(1);
#pragma unroll
    for (int i = 0; i < 4; ++i)
#pragma unroll
      for (int n = 0; n < 4; ++n)
        acc[i][n] = __builtin_amdgcn_mfma_f32_16x16x32_f16(af[i], bf[n], acc[i][n], 0, 0, 0);
    __builtin_amdgcn_s_setprio(0);
    __builtin_amdgcn_s_barrier();

    // -------- phase odd (qm=1): m-frags 4..7, bf reused ---------------------
#pragma unroll
    for (int i = 0; i < 4; ++i) af[i] = *(const half8*)(as + 2048 + i * 512);
#pragma unroll
    for (int j = 0; j < 2; ++j)  // stage B(ks)
      async_copy16(Bb + sg + ks * 32 + j * lK128, Br + ssl * 8192 + ldst + j * 4096);
    __builtin_amdgcn_s_barrier();
    asm volatile("s_waitcnt lgkmcnt(0)" ::: "memory");
    __builtin_amdgcn_sched_barrier(0);
    __builtin_amdgcn_s_setprio(1);
#pragma unroll
    for (int i = 0; i < 4; ++i)
#pragma unroll
      for (int n = 0; n < 4; ++n)
        acc[4 + i][n] = __builtin_amdgcn_mfma_f32_16x16x32_f16(af[i], bf[n], acc[4 + i][n], 0, 0, 0);
    __builtin_amdgcn_s_setprio(0);
    // Slice boundary: publish slot (kc+1)&3. Issued after its 4 loads:
    // A/B(kc+2) + A/B(kc+3) = 8 loads -> vmcnt(8) lands exactly what's needed.
    asm volatile("s_waitcnt vmcnt(8)" ::: "memory");
    __builtin_amdgcn_s_barrier();
  }

  // Epilogue. acc[m][n][i] = C[wm*128 + m*16 + fq*4 + i][wn*64 + n*16 + frow]
  if (OMODE == 0 || OMODE == 1) {
#pragma unroll
    for (int n = 0; n < 4; ++n) {
      const int cg = blockIdx.y * 256 + wn * 64 + n * 16 + frow;
      const float bvv = bias[cg];
#pragma unroll
      for (int m = 0; m < 8; ++m) {
        const int rg = blockIdx.x * 256 + wm * 128 + m * 16 + fq * 4;
        if (OMODE == 0) {
#pragma unroll
          for (int i = 0; i < 4; ++i)
            ((_Float16*)out)[(long)(rg + i) * N + cg] = (_Float16)(acc[m][n][i] + bvv);
        } else {  // Vt[b][n][s], s contiguous -> 8B store
          const long bb = rg >> 11;
          const int s = rg & 2047;
          half4v hv;
#pragma unroll
          for (int i = 0; i < 4; ++i) hv[i] = (_Float16)(acc[m][n][i] + bvv);
          *(half4v*)((_Float16*)out + bb * (2048l * 1024) + (long)cg * 2048 + s) = hv;
        }
      }
    }
  } else {
#pragma unroll
    for (int n = 0; n < 4; ++n) {
      const int cg = blockIdx.y * 256 + wn * 64 + n * 16 + frow;
#pragma unroll
      for (int m = 0; m < 8; ++m) {
        const int rgl = blockIdx.x * 256 + wm * 128 + m * 16 + fq * 4;
#pragma unroll
        for (int i = 0; i < 4; ++i) {
          if (OMODE == 2)
            ((float*)out + bz * sO)[(long)(rgl + i) * N + cg] = acc[m][n][i];
          else
            ((_Float16*)out + bz * sO)[(long)(rgl + i) * N + cg] = (_Float16)acc[m][n][i];
        }
      }
    }
  }
}

// ---------------- row softmax: S fp16 [rows][2048] -> P fp16 ----------------
__global__ __launch_bounds__(256) void softmax_rows(const _Float16* __restrict__ S,
                                                    _Float16* __restrict__ P) {
  const long row = blockIdx.x;
  const _Float16* src = S + row * 2048;
  _Float16* dst = P + row * 2048;
  const int tid = threadIdx.x;

  half8 v = ((const half8*)src)[tid];  // elems 8t..8t+7
  float f[8];
#pragma unroll
  for (int i = 0; i < 8; i++) f[i] = (float)v[i];

  float m = fmaxf(fmaxf(fmaxf(f[0], f[1]), fmaxf(f[2], f[3])),
                  fmaxf(fmaxf(f[4], f[5]), fmaxf(f[6], f[7])));
#pragma unroll
  for (int o = 32; o > 0; o >>= 1) m = fmaxf(m, __shfl_xor(m, o, 64));
  __shared__ float redm[4];
  if ((tid & 63) == 0) redm[tid >> 6] = m;
  __syncthreads();
  m = fmaxf(fmaxf(redm[0], redm[1]), fmaxf(redm[2], redm[3]));

  float e[8], s = 0.f;
#pragma unroll
  for (int i = 0; i < 8; i++) { e[i] = __expf(f[i] - m); s += e[i]; }
#pragma unroll
  for (int o = 32; o > 0; o >>= 1) s += __shfl_xor(s, o, 64);
  __shared__ float reds[4];
  if ((tid & 63) == 0) reds[tid >> 6] = s;
  __syncthreads();
  s = (reds[0] + reds[1]) + (reds[2] + reds[3]);
  const float inv = 1.f / s;

  half8 h;
#pragma unroll
  for (int i = 0; i < 8; i++) h[i] = (_Float16)(e[i] * inv);
  ((half8*)dst)[tid] = h;
}

extern "C" void kernel_launch(void* const* d_in, const int* in_sizes, int n_in,
                              void* d_out, int out_size, void* d_ws, size_t ws_size,
                              hipStream_t stream) {
  const float* target = (const float*)d_in[0];
  const float* non_target = (const float*)d_in[1];
  const float* Wq = (const float*)d_in[2];
  const float* bq = (const float*)d_in[3];
  const float* Wk = (const float*)d_in[4];
  const float* bk = (const float*)d_in[5];
  const float* Wv = (const float*)d_in[6];
  const float* bv = (const float*)d_in[7];

  char* ws = (char*)d_ws;
  const size_t MB = 1ull << 20;
  _Float16* tgt16 = (_Float16*)(ws);             // 32 MiB
  _Float16* ntg16 = (_Float16*)(ws + 32 * MB);   // 32 MiB
  _Float16* S16 = (_Float16*)(ws);               // 64 MiB (over tgt16/ntg16, phase 3)
  _Float16* P16 = (_Float16*)(ws + 64 * MB);     // 64 MiB
  _Float16* Q16 = (_Float16*)(ws + 128 * MB);    // 32 MiB
  _Float16* K16 = (_Float16*)(ws + 160 * MB);    // 32 MiB
  _Float16* Vt16 = (_Float16*)(ws + 192 * MB);   // 32 MiB
  _Float16* Wq16 = (_Float16*)(ws + 224 * MB);   // 2 MiB
  _Float16* Wk16 = (_Float16*)(ws + 226 * MB);   // 2 MiB
  _Float16* Wv16 = (_Float16*)(ws + 228 * MB);   // 2 MiB

  const long nBig = 8l * 2048 * 1024;  // 16.78M
  const long nW = 1024l * 1024;

  // 1. casts
  cast_f32_f16<<<8192, 256, 0, stream>>>(target, tgt16, nBig);
  cast_f32_f16<<<8192, 256, 0, stream>>>(non_target, ntg16, nBig);
  cast_f32_f16<<<512, 256, 0, stream>>>(Wq, Wq16, nW);
  cast_f32_f16<<<512, 256, 0, stream>>>(Wk, Wk16, nW);
  cast_f32_f16<<<512, 256, 0, stream>>>(Wv, Wv16, nW);

  // 2. projections: [16384,1024] = [16384,1024] x [1024,1024]^T + bias
  gemm256<0><<<dim3(64, 4, 1), 512, 0, stream>>>(tgt16, Wq16, bq, Q16, 1024, 1024, 0, 0, 0);
  gemm256<0><<<dim3(64, 4, 1), 512, 0, stream>>>(ntg16, Wk16, bk, K16, 1024, 1024, 0, 0, 0);
  gemm256<1><<<dim3(64, 4, 1), 512, 0, stream>>>(ntg16, Wv16, bv, Vt16, 1024, 1024, 0, 0, 0);

  // 3. scores: per batch [2048,2048] = Q_b x K_b^T (fp16 out)
  gemm256<3><<<dim3(8, 8, 8), 512, 0, stream>>>(Q16, K16, nullptr, S16, 1024, 2048,
                                                2048l * 1024, 2048l * 1024, 2048l * 2048);

  // 4. softmax rows -> P fp16
  softmax_rows<<<16384, 256, 0, stream>>>(S16, P16);

  // 5. out: per batch [2048,1024] = P_b x Vt_b^T (fp32 out to d_out)
  gemm256<2><<<dim3(8, 4, 8), 512, 0, stream>>>(P16, Vt16, nullptr, (float*)d_out, 2048, 1024,
                                                2048l * 2048, 1024l * 2048, 2048l * 1024);
}

// Round 2
// 488.326 us; speedup vs baseline: 1.0142x; 1.0142x over previous
//
#include <hip/hip_runtime.h>

// CustomAttention: out = softmax((x_t Wq^T + bq)(x_nt Wk^T + bk)^T) (x_nt Wv^T + bv)
// B=8, SQ=SKV=2048, D=1024. fp32 in/out, fp16 MFMA compute (fp32 accumulate).
//
// Round 4: round-3's 8-phase port serialized LDS and MFMA (4 barriers/slice,
// lockstep; MfmaUtil 33%). This round: register-level fragment double-buffer,
// ONE barrier per K=32 slice:
//   slice kc: [stage slice kc+3 (4 gloads)] [prefetch slice kc+1 frags
//   (12 ds_read_b128) into shadow regs] [sched_barrier] [32 MFMA from current
//   regs, setprio(1)] [lgkmcnt(0)+sched_barrier] [vmcnt(4)] [s_barrier]
// Invariants (ring of 4 slots per operand, depth-3 staging):
//  - barrier entering slice kc publishes slot kc+1: its loads were issued at
//    slice kc-2 (~2 slices cover); vmcnt(4) leaves only slice kc+2's 4 loads
//    in flight. Never drains to 0 in the loop.
//  - gloads at kc overwrite slot (kc+3)&3 = (kc-1)&3, last read (prefetch)
//    during slice kc-2, lgkm-drained + barrier-separated -> safe.
//  - tail: staging/prefetch clamp to NK-1 -> duplicate same-value writes
//    (benign race) keep counter arithmetic uniform.
//  - LDS layout + XOR granule swizzle identical to the harness-verified r3
//    kernel (bank-conflict counter 0); only the schedule changed.
//
// ws layout (224 MiB peak + 6 MiB weights):
//  [0,32)    tgt16   -- dead after projections | S16 [0,64) written by QK
//  [32,64)   ntg16   -- dead after projections |
//  [64,128)  P16     (written by softmax)
//  [128,160) Q16
//  [160,192) K16
//  [192,224) Vt16
//  [224,230) Wq16/Wk16/Wv16

typedef _Float16 half8 __attribute__((ext_vector_type(8)));
typedef _Float16 half4v __attribute__((ext_vector_type(4)));
typedef float floatx4 __attribute__((ext_vector_type(4)));

__device__ __forceinline__ void async_copy16(const _Float16* g, _Float16* l) {
  __builtin_amdgcn_global_load_lds(
      (const __attribute__((address_space(1))) void*)g,
      (__attribute__((address_space(3))) void*)l,
      16, 0, 0);
}

// ---------------- cast fp32 -> fp16 (8 elems/thread) ----------------
__global__ __launch_bounds__(256) void cast_f32_f16(const float* __restrict__ src,
                                                    _Float16* __restrict__ dst, long n) {
  long i = ((long)blockIdx.x * 256 + threadIdx.x) * 8;
  if (i >= n) return;
  float4 a = *(const float4*)(src + i);
  float4 b = *(const float4*)(src + i + 4);
  half8 h;
  h[0] = (_Float16)a.x; h[1] = (_Float16)a.y; h[2] = (_Float16)a.z; h[3] = (_Float16)a.w;
  h[4] = (_Float16)b.x; h[5] = (_Float16)b.y; h[6] = (_Float16)b.z; h[7] = (_Float16)b.w;
  *(half8*)(dst + i) = h;
}

// ---------------- fp16 BT GEMM, 256x256 tile, 1-barrier/slice pipeline -----
// C[m,n] = sum_k A[m,k]*B[n,k] (+bias[n])
// OMODE 0: fp16 out row-major [*,N] + bias
// OMODE 1: fp16 out V-transposed: row r -> (b=r>>11, s=r&2047), Vt[b][n][s], + bias
// OMODE 2: fp32 out row-major [*,N] per batch (no bias)
// OMODE 3: fp16 out row-major [*,N] per batch (no bias)  [S scores]

// One K=32 slice: stage slice KS=min(KC+3,NK-1); prefetch frags of slice
// PF=min(KC+1,NK-1) into (AFN,BFN); 32 MFMA from (AFC,BFC); wait; barrier.
#define GSLICE(KC, AFC, BFC, AFN, BFN)                                          \
  {                                                                             \
    const int kc_ = (KC);                                                       \
    int ks_ = kc_ + 3; if (ks_ > NK - 1) ks_ = NK - 1;                          \
    int pf_ = kc_ + 1; if (pf_ > NK - 1) pf_ = NK - 1;                          \
    _Float16* sa_ = Ar + (ks_ & 3) * 8192 + ldst;                               \
    _Float16* sb_ = Br + (ks_ & 3) * 8192 + ldst;                               \
    const long go_ = (long)ks_ * 32;                                            \
    async_copy16(Abg + go_, sa_);                                               \
    async_copy16(Abg + go_ + lK128, sa_ + 4096);                                \
    async_copy16(Bbg + go_, sb_);                                               \
    async_copy16(Bbg + go_ + lK128, sb_ + 4096);                                \
    const _Float16* pa_ = Ar + (pf_ & 3) * 8192 + wm * 4096 + aoff;             \
    const _Float16* pb_ = Br + (pf_ & 3) * 8192 + wn * 2048 + aoff;             \
    _Pragma("unroll") for (int n = 0; n < 4; ++n)                               \
      BFN[n] = *(const half8*)(pb_ + n * 512);                                  \
    _Pragma("unroll") for (int i = 0; i < 8; ++i)                               \
      AFN[i] = *(const half8*)(pa_ + (i & 3) * 512 + (i >> 2) * 2048);          \
    __builtin_amdgcn_sched_barrier(0);                                          \
    __builtin_amdgcn_s_setprio(1);                                              \
    _Pragma("unroll") for (int i = 0; i < 8; ++i)                               \
      _Pragma("unroll") for (int n = 0; n < 4; ++n)                             \
        acc[i][n] = __builtin_amdgcn_mfma_f32_16x16x32_f16(AFC[i], BFC[n],      \
                                                           acc[i][n], 0, 0, 0); \
    __builtin_amdgcn_s_setprio(0);                                              \
    asm volatile("s_waitcnt lgkmcnt(0)" ::: "memory");                          \
    __builtin_amdgcn_sched_barrier(0);                                          \
    asm volatile("s_waitcnt vmcnt(4)" ::: "memory");                            \
    __builtin_amdgcn_s_barrier();                                               \
  }

template <int OMODE>
__global__ __launch_bounds__(512, 2) void gemm256(const _Float16* __restrict__ A,
                                                  const _Float16* __restrict__ Bm,
                                                  const float* __restrict__ bias,
                                                  void* __restrict__ out,
                                                  int K, int N,
                                                  long sA, long sB, long sO) {
  // A-ring: 4 slots x 8192 halfs; B-ring same. 128 KiB.
  __shared__ __attribute__((aligned(16))) _Float16 lds[65536];
  _Float16* Ar = lds;
  _Float16* Br = lds + 32768;

  const int tid = threadIdx.x;
  const int lane = tid & 63;
  const int wave = tid >> 6;
  const int wm = wave >> 2;   // 0..1  (M half)
  const int wn = wave & 3;    // 0..3  (N quarter)
  const int frow = lane & 15;
  const int fq = (lane >> 4) & 3;
  const long bz = blockIdx.z;

  // Staging: slice = 256 rows x 32 halfs = 1024 x 16B chunks; thread owns
  // chunks c = tid + 512j (j=0,1). Physical chunk c -> lds row l=c>>3,
  // phys granule c&7; logical granule = (c&7) ^ (l&7); global (row,k):
  // row = 2l + (glog>>2), k-granule = glog&3. 512j keeps l&7 and c&7 fixed.
  const int glog = (tid & 7) ^ ((tid >> 3) & 7);
  const long sg = (long)(2 * (tid >> 3) + (glog >> 2)) * K + (glog & 3) * 8;
  const int ldst = tid * 8;            // halfs within slot; j adds 4096
  const long lK128 = (long)K * 128;    // j=1 adds 128 M-rows

  const _Float16* Abg = A + bz * sA + (long)blockIdx.x * 256 * K + sg;
  const _Float16* Bbg = Bm + bz * sB + (long)blockIdx.y * 256 * K + sg;

  // Fragment reads: logical (R, fq) -> l = R>>1, g = (R&1)*4+fq,
  // g_phys = g ^ (l&7). All frag bases are multiples of 16 rows -> l&7 = frow>>1.
  const int gphys = ((frow & 1) * 4 + fq) ^ (frow >> 1);
  const int aoff = (frow >> 1) * 64 + gphys * 8;  // lane-invariant across frags

  floatx4 acc[8][4];
#pragma unroll
  for (int m = 0; m < 8; ++m)
#pragma unroll
    for (int n = 0; n < 4; ++n) acc[m][n] = (floatx4){0.f, 0.f, 0.f, 0.f};

  const int NK = K >> 5;  // 32-wide K slices (NK = 32 or 64 here, always even)

  // Prologue: stage slices 0,1,2 (12 loads). vmcnt(4) -> slices 0,1 landed.
#pragma unroll
  for (int kp = 0; kp < 3; ++kp) {
    async_copy16(Abg + kp * 32, Ar + kp * 8192 + ldst);
    async_copy16(Abg + kp * 32 + lK128, Ar + kp * 8192 + ldst + 4096);
    async_copy16(Bbg + kp * 32, Br + kp * 8192 + ldst);
    async_copy16(Bbg + kp * 32 + lK128, Br + kp * 8192 + ldst + 4096);
  }
  asm volatile("s_waitcnt vmcnt(4)" ::: "memory");
  __builtin_amdgcn_s_barrier();

  // Prefetch slice 0 fragments into the A-register set.
  half8 afA[8], bfA[4], afB[8], bfB[4];
  {
    const _Float16* pa = Ar + wm * 4096 + aoff;  // slot 0
    const _Float16* pb = Br + wn * 2048 + aoff;
#pragma unroll
    for (int n = 0; n < 4; ++n) bfA[n] = *(const half8*)(pb + n * 512);
#pragma unroll
    for (int i = 0; i < 8; ++i) afA[i] = *(const half8*)(pa + (i & 3) * 512 + (i >> 2) * 2048);
  }
  asm volatile("s_waitcnt lgkmcnt(0)" ::: "memory");
  __builtin_amdgcn_sched_barrier(0);

  for (int kc = 0; kc < NK; kc += 2) {
    GSLICE(kc, afA, bfA, afB, bfB);
    GSLICE(kc + 1, afB, bfB, afA, bfA);
  }

  // Epilogue. acc[m][n][i] = C[wm*128 + m*16 + fq*4 + i][wn*64 + n*16 + frow]
  if (OMODE == 0 || OMODE == 1) {
#pragma unroll
    for (int n = 0; n < 4; ++n) {
      const int cg = blockIdx.y * 256 + wn * 64 + n * 16 + frow;
      const float bvv = bias[cg];
#pragma unroll
      for (int m = 0; m < 8; ++m) {
        const int rg = blockIdx.x * 256 + wm * 128 + m * 16 + fq * 4;
        if (OMODE == 0) {
#pragma unroll
          for (int i = 0; i < 4; ++i)
            ((_Float16*)out)[(long)(rg + i) * N + cg] = (_Float16)(acc[m][n][i] + bvv);
        } else {  // Vt[b][n][s], s contiguous -> 8B store
          const long bb = rg >> 11;
          const int s = rg & 2047;
          half4v hv;
#pragma unroll
          for (int i = 0; i < 4; ++i) hv[i] = (_Float16)(acc[m][n][i] + bvv);
          *(half4v*)((_Float16*)out + bb * (2048l * 1024) + (long)cg * 2048 + s) = hv;
        }
      }
    }
  } else {
#pragma unroll
    for (int n = 0; n < 4; ++n) {
      const int cg = blockIdx.y * 256 + wn * 64 + n * 16 + frow;
#pragma unroll
      for (int m = 0; m < 8; ++m) {
        const int rgl = blockIdx.x * 256 + wm * 128 + m * 16 + fq * 4;
#pragma unroll
        for (int i = 0; i < 4; ++i) {
          if (OMODE == 2)
            ((float*)out + bz * sO)[(long)(rgl + i) * N + cg] = acc[m][n][i];
          else
            ((_Float16*)out + bz * sO)[(long)(rgl + i) * N + cg] = (_Float16)acc[m][n][i];
        }
      }
    }
  }
}

// ---------------- row softmax: S fp16 [rows][2048] -> P fp16 ----------------
__global__ __launch_bounds__(256) void softmax_rows(const _Float16* __restrict__ S,
                                                    _Float16* __restrict__ P) {
  const long row = blockIdx.x;
  const _Float16* src = S + row * 2048;
  _Float16* dst = P + row * 2048;
  const int tid = threadIdx.x;

  half8 v = ((const half8*)src)[tid];  // elems 8t..8t+7
  float f[8];
#pragma unroll
  for (int i = 0; i < 8; i++) f[i] = (float)v[i];

  float m = fmaxf(fmaxf(fmaxf(f[0], f[1]), fmaxf(f[2], f[3])),
                  fmaxf(fmaxf(f[4], f[5]), fmaxf(f[6], f[7])));
#pragma unroll
  for (int o = 32; o > 0; o >>= 1) m = fmaxf(m, __shfl_xor(m, o, 64));
  __shared__ float redm[4];
  if ((tid & 63) == 0) redm[tid >> 6] = m;
  __syncthreads();
  m = fmaxf(fmaxf(redm[0], redm[1]), fmaxf(redm[2], redm[3]));

  float e[8], s = 0.f;
#pragma unroll
  for (int i = 0; i < 8; i++) { e[i] = __expf(f[i] - m); s += e[i]; }
#pragma unroll
  for (int o = 32; o > 0; o >>= 1) s += __shfl_xor(s, o, 64);
  __shared__ float reds[4];
  if ((tid & 63) == 0) reds[tid >> 6] = s;
  __syncthreads();
  s = (reds[0] + reds[1]) + (reds[2] + reds[3]);
  const float inv = 1.f / s;

  half8 h;
#pragma unroll
  for (int i = 0; i < 8; i++) h[i] = (_Float16)(e[i] * inv);
  ((half8*)dst)[tid] = h;
}

extern "C" void kernel_launch(void* const* d_in, const int* in_sizes, int n_in,
                              void* d_out, int out_size, void* d_ws, size_t ws_size,
                              hipStream_t stream) {
  const float* target = (const float*)d_in[0];
  const float* non_target = (const float*)d_in[1];
  const float* Wq = (const float*)d_in[2];
  const float* bq = (const float*)d_in[3];
  const float* Wk = (const float*)d_in[4];
  const float* bk = (const float*)d_in[5];
  const float* Wv = (const float*)d_in[6];
  const float* bv = (const float*)d_in[7];

  char* ws = (char*)d_ws;
  const size_t MB = 1ull << 20;
  _Float16* tgt16 = (_Float16*)(ws);             // 32 MiB
  _Float16* ntg16 = (_Float16*)(ws + 32 * MB);   // 32 MiB
  _Float16* S16 = (_Float16*)(ws);               // 64 MiB (over tgt16/ntg16, phase 3)
  _Float16* P16 = (_Float16*)(ws + 64 * MB);     // 64 MiB
  _Float16* Q16 = (_Float16*)(ws + 128 * MB);    // 32 MiB
  _Float16* K16 = (_Float16*)(ws + 160 * MB);    // 32 MiB
  _Float16* Vt16 = (_Float16*)(ws + 192 * MB);   // 32 MiB
  _Float16* Wq16 = (_Float16*)(ws + 224 * MB);   // 2 MiB
  _Float16* Wk16 = (_Float16*)(ws + 226 * MB);   // 2 MiB
  _Float16* Wv16 = (_Float16*)(ws + 228 * MB);   // 2 MiB

  const long nBig = 8l * 2048 * 1024;  // 16.78M
  const long nW = 1024l * 1024;

  // 1. casts
  cast_f32_f16<<<8192, 256, 0, stream>>>(target, tgt16, nBig);
  cast_f32_f16<<<8192, 256, 0, stream>>>(non_target, ntg16, nBig);
  cast_f32_f16<<<512, 256, 0, stream>>>(Wq, Wq16, nW);
  cast_f32_f16<<<512, 256, 0, stream>>>(Wk, Wk16, nW);
  cast_f32_f16<<<512, 256, 0, stream>>>(Wv, Wv16, nW);

  // 2. projections: [16384,1024] = [16384,1024] x [1024,1024]^T + bias
  gemm256<0><<<dim3(64, 4, 1), 512, 0, stream>>>(tgt16, Wq16, bq, Q16, 1024, 1024, 0, 0, 0);
  gemm256<0><<<dim3(64, 4, 1), 512, 0, stream>>>(ntg16, Wk16, bk, K16, 1024, 1024, 0, 0, 0);
  gemm256<1><<<dim3(64, 4, 1), 512, 0, stream>>>(ntg16, Wv16, bv, Vt16, 1024, 1024, 0, 0, 0);

  // 3. scores: per batch [2048,2048] = Q_b x K_b^T (fp16 out)
  gemm256<3><<<dim3(8, 8, 8), 512, 0, stream>>>(Q16, K16, nullptr, S16, 1024, 2048,
                                                2048l * 1024, 2048l * 1024, 2048l * 2048);

  // 4. softmax rows -> P fp16
  softmax_rows<<<16384, 256, 0, stream>>>(S16, P16);

  // 5. out: per batch [2048,1024] = P_b x Vt_b^T (fp32 out to d_out)
  gemm256<2><<<dim3(8, 4, 8), 512, 0, stream>>>(P16, Vt16, nullptr, (float*)d_out, 2048, 1024,
                                                2048l * 2048, 1024l * 2048, 2048l * 1024);
}